// Round 8
// baseline (77.055 us; speedup 1.0000x reference)
//
#include <hip/hip_runtime.h>

#define DIMS 256
#define HK 64
#define NB 4
#define NT 4096
#define BT (NB * NT)

typedef unsigned short u16;
typedef unsigned int u32;

using f32x4  = __attribute__((ext_vector_type(4))) float;
using bf16x8 = __attribute__((ext_vector_type(8))) short;

__device__ __forceinline__ u16 f2bf(float f) {
    u32 u = __float_as_uint(f);
    u = (u + 0x7FFFu + ((u >> 16) & 1u)) >> 16;  // RNE; inputs finite
    return (u16)u;
}
__device__ __forceinline__ u32 pack2(float a, float b) {
    return (u32)f2bf(a) | ((u32)f2bf(b) << 16);
}
__device__ __forceinline__ float bf2f(short h) {
    return __uint_as_float(((u32)(u16)h) << 16);
}
__device__ __forceinline__ bf16x8 ldb8(const u16* p) {
    return *reinterpret_cast<const bf16x8*>(p);
}
__device__ __forceinline__ u32 cvtpk(float a, float b) {
    u32 r;
    asm("v_cvt_pk_bf16_f32 %0, %1, %2" : "=v"(r) : "v"(a), "v"(b));
    return r;
}
__device__ __forceinline__ bf16x8 cvt8(const float* p) {
    f32x4 a = *reinterpret_cast<const f32x4*>(p);
    f32x4 b = *reinterpret_cast<const f32x4*>(p + 4);
    union { u32 w[4]; bf16x8 v; } u;
    u.w[0] = pack2(a[0], a[1]); u.w[1] = pack2(a[2], a[3]);
    u.w[2] = pack2(b[0], b[1]); u.w[3] = pack2(b[2], b[3]);
    return u.v;
}

// ---- prep: W transpose/convert only: Wt[m][col][k] = bf16(W[m][k][col]) ----
__global__ __launch_bounds__(256) void prep_kernel(
    const float* __restrict__ wk, const float* __restrict__ wq,
    const float* __restrict__ wv, u16* __restrict__ Wt)
{
    const int i = (int)(blockIdx.x * 256 + threadIdx.x);  // 0..12287
    const int e0 = i * 4;
    const int m = e0 >> 14;
    const int r = e0 & 16383;
    const int col = r >> 8;
    const int k = r & 255;
    const float* w = (m == 0) ? wk : (m == 1) ? wq : wv;
    u32 w0 = pack2(w[(k + 0) * HK + col], w[(k + 1) * HK + col]);
    u32 w1 = pack2(w[(k + 2) * HK + col], w[(k + 3) * HK + col]);
    u32* p = reinterpret_cast<u32*>(Wt + e0);
    p[0] = w0; p[1] = w1;
}

// ---- proj: fused x->out copy + bf16 MFMA GEMMs (K,Q,V) per 16-row tile ----
__global__ __launch_bounds__(64) void proj_kernel(
    const float* __restrict__ x, const u16* __restrict__ Wt,
    float* __restrict__ out,
    u16* __restrict__ Qb, u16* __restrict__ Kb, u16* __restrict__ Vt)
{
    const int l = (int)threadIdx.x;
    const int lo = l & 15;
    const int g = l >> 4;
    const int q0 = (int)blockIdx.x * 16;

    // copy x tile -> out[...,0:256] (coalesced f32x4)
    const f32x4* x4 = reinterpret_cast<const f32x4*>(x);
    f32x4* out4 = reinterpret_cast<f32x4*>(out);
    #pragma unroll
    for (int c = 0; c < 16; ++c) {
        f32x4 v = x4[(size_t)(q0 + c) * 64 + l];
        out4[(size_t)(q0 + c) * 80 + l] = v;
    }

    // A fragments from x (L1-hot re-read)
    bf16x8 a[8];
    #pragma unroll
    for (int kf = 0; kf < 8; ++kf)
        a[kf] = cvt8(x + (size_t)(q0 + lo) * DIMS + kf * 32 + g * 8);

    #pragma unroll
    for (int m = 0; m < 3; ++m) {
        const u16* wb = Wt + m * (HK * DIMS);
        f32x4 acc[4];
        #pragma unroll
        for (int c = 0; c < 4; ++c) acc[c] = f32x4{0.f, 0.f, 0.f, 0.f};

        __builtin_amdgcn_s_setprio(1);
        #pragma unroll
        for (int c = 0; c < 4; ++c) {
            #pragma unroll
            for (int kf = 0; kf < 8; ++kf) {
                bf16x8 bf = ldb8(wb + (size_t)(16 * c + lo) * DIMS + kf * 32 + g * 8);
                acc[c] = __builtin_amdgcn_mfma_f32_16x16x32_bf16(a[kf], bf, acc[c], 0, 0, 0);
            }
        }
        __builtin_amdgcn_s_setprio(0);

        if (m == 2) {
            #pragma unroll
            for (int c = 0; c < 4; ++c)
                #pragma unroll
                for (int ii = 0; ii < 4; ++ii) {
                    const int grow = q0 + 4 * g + ii;
                    Vt[(size_t)((grow >> 12) * HK + 16 * c + lo) * NT + (grow & (NT - 1))] =
                        f2bf(acc[c][ii]);
                }
        } else {
            const float sc = (m == 1) ? 0.125f * 1.44269504f : 1.0f;
            u16* dst = (m == 1) ? Qb : Kb;
            #pragma unroll
            for (int c = 0; c < 4; ++c)
                #pragma unroll
                for (int ii = 0; ii < 4; ++ii)
                    dst[(size_t)(q0 + 4 * g + ii) * HK + 16 * c + lo] = f2bf(acc[c][ii] * sc);
        }
    }
}

// ==== attention: VERBATIM Round-4 kernel (passed, absmax 0.0625) ====
// swapped QK^T + in-register P via cvt_pk/permlane; 1 wave, 32 q-rows.
template<bool MASK>
__device__ __forceinline__ void qk32(
    const u16* __restrict__ Kb_b, int s0, int q0,
    const bf16x8 (&qf)[2][2], float (&pls)[2], bf16x8 (&pa)[2],
    int lo, int g)
{
    bf16x8 kk[2][2];
    #pragma unroll
    for (int kh = 0; kh < 2; ++kh)
        #pragma unroll
        for (int kf = 0; kf < 2; ++kf)
            kk[kh][kf] = ldb8(Kb_b + (size_t)(s0 + 16 * kh + lo) * HK + kf * 32 + g * 8);

    const f32x4 c28 = f32x4{-28.f, -28.f, -28.f, -28.f};  // fold exp2(s-28) bias
    f32x4 sv[2][2];
    __builtin_amdgcn_s_setprio(1);
    #pragma unroll
    for (int rh = 0; rh < 2; ++rh)
        #pragma unroll
        for (int kh = 0; kh < 2; ++kh) {
            sv[rh][kh] = __builtin_amdgcn_mfma_f32_16x16x32_bf16(kk[kh][0], qf[rh][0], c28, 0, 0, 0);
            sv[rh][kh] = __builtin_amdgcn_mfma_f32_16x16x32_bf16(kk[kh][1], qf[rh][1], sv[rh][kh], 0, 0, 0);
        }
    __builtin_amdgcn_s_setprio(0);

    #pragma unroll
    for (int rh = 0; rh < 2; ++rh) {
        float p0[4], p1[4];
        #pragma unroll
        for (int ii = 0; ii < 4; ++ii) {
            float v0 = sv[rh][0][ii];
            float v1 = sv[rh][1][ii];
            if (MASK) {
                const int qr = q0 + 16 * rh + lo;
                if (s0 + 4 * g + ii > qr)      v0 = -1e30f;
                if (s0 + 16 + 4 * g + ii > qr) v1 = -1e30f;
            }
            p0[ii] = __builtin_amdgcn_exp2f(v0);
            p1[ii] = __builtin_amdgcn_exp2f(v1);
            pls[rh] += p0[ii] + p1[ii];
        }
        u32 a0 = cvtpk(p0[0], p0[1]), a1 = cvtpk(p0[2], p0[3]);
        u32 b0 = cvtpk(p1[0], p1[1]), b1 = cvtpk(p1[2], p1[3]);
        asm("v_permlane32_swap_b32 %0, %1" : "+v"(a0), "+v"(b0));
        asm("v_permlane16_swap_b32 %0, %1" : "+v"(a0), "+v"(b0));
        asm("v_permlane32_swap_b32 %0, %1" : "+v"(a1), "+v"(b1));
        asm("v_permlane16_swap_b32 %0, %1" : "+v"(a1), "+v"(b1));
        union { u32 w[4]; bf16x8 v; } u;
        u.w[0] = a0; u.w[1] = a1; u.w[2] = b0; u.w[3] = b1;
        pa[rh] = u.v;
    }
}

template<int NK, bool MASK>
__device__ __forceinline__ void body(
    const u16* __restrict__ Kb_b, const u16* __restrict__ Vb, int s0,
    const bf16x8 (&qf)[2][2], float (&pls)[2], f32x4 (&o)[2][4],
    int lo, int g, int q0)
{
    bf16x8 vf[NK][4];
    #pragma unroll
    for (int kf = 0; kf < NK; ++kf)
        #pragma unroll
        for (int c = 0; c < 4; ++c)
            vf[kf][c] = ldb8(Vb + (size_t)(16 * c + lo) * NT + s0 + kf * 32 + g * 8);

    #pragma unroll
    for (int t = 0; t < NK; ++t) {
        bf16x8 pa[2];
        qk32<MASK>(Kb_b, s0 + t * 32, q0, qf, pls, pa, lo, g);
        __builtin_amdgcn_s_setprio(1);
        #pragma unroll
        for (int rh = 0; rh < 2; ++rh)
            #pragma unroll
            for (int c = 0; c < 4; ++c)
                o[rh][c] = __builtin_amdgcn_mfma_f32_16x16x32_bf16(pa[rh], vf[t][c], o[rh][c], 0, 0, 0);
        __builtin_amdgcn_s_setprio(0);
    }
}

__global__ __launch_bounds__(64) void attn_kernel(
    const u16* __restrict__ Qb, const u16* __restrict__ Kb,
    const u16* __restrict__ Vt, u16* __restrict__ Opb, float* __restrict__ lp,
    const int S)
{
    const int l = (int)threadIdx.x;
    const int lo = l & 15;
    const int g = l >> 4;

    const int bid = (int)blockIdx.x;
    const int per = 4 * S;
    const int j = 127 - bid / per;   // long blocks first
    const int r = bid % per;
    const int b = r / S;
    const int s = r % S;

    const int q0 = j * 32;
    const int nkv = j + 1;                 // 32-key tiles
    const int it0 = (s * nkv) / S;
    const int it1 = ((s + 1) * nkv) / S;

    const u16* Kb_b = Kb + (size_t)b * NT * HK;
    const u16* Vb = Vt + (size_t)b * HK * NT;

    bf16x8 qf[2][2];  // B-operand: col = q-row, k = dim
    #pragma unroll
    for (int rh = 0; rh < 2; ++rh)
        #pragma unroll
        for (int kf = 0; kf < 2; ++kf)
            qf[rh][kf] = ldb8(Qb + (size_t)(b * NT + q0 + 16 * rh + lo) * HK + kf * 32 + g * 8);

    f32x4 o[2][4];
    float pls[2] = {0.f, 0.f};
    #pragma unroll
    for (int rh = 0; rh < 2; ++rh)
        #pragma unroll
        for (int c = 0; c < 4; ++c) o[rh][c] = f32x4{0.f, 0.f, 0.f, 0.f};

    int it = it0;
    const int itE = (s == S - 1) ? it1 - 1 : it1;  // unmasked range end
    for (; it + 1 < itE; it += 2)
        body<2, false>(Kb_b, Vb, it * 32, qf, pls, o, lo, g, q0);
    if (it < itE)
        body<1, false>(Kb_b, Vb, it * 32, qf, pls, o, lo, g, q0);
    if (s == S - 1)
        body<1, true>(Kb_b, Vb, (nkv - 1) * 32, qf, pls, o, lo, g, q0);

    const size_t rowbase = (size_t)s * BT + (size_t)b * NT + q0;
    #pragma unroll
    for (int rh = 0; rh < 2; ++rh) {
        #pragma unroll
        for (int c = 0; c < 4; ++c)
            #pragma unroll
            for (int ii = 0; ii < 4; ++ii)
                Opb[(rowbase + 16 * rh + 4 * g + ii) * HK + 16 * c + lo] = f2bf(o[rh][c][ii]);
        float sum = pls[rh];
        sum += __shfl_xor(sum, 16);
        sum += __shfl_xor(sum, 32);
        if (l < 16) lp[rowbase + 16 * rh + lo] = sum;
    }
}

// ---- merge: out[...,256:320] = sum_s(Opb) / sum_s(lp) ----
__global__ __launch_bounds__(256) void merge_kernel(
    const u16* __restrict__ Opb, const float* __restrict__ lp,
    float* __restrict__ out, const int S)
{
    const int idx = (int)(blockIdx.x * 256 + threadIdx.x);  // [0, BT*8)
    const int row = idx >> 3;
    const int c8 = (idx & 7) * 8;

    float li = 0.f;
    for (int s = 0; s < S; ++s) li += lp[(size_t)s * BT + row];

    float acc[8];
    #pragma unroll
    for (int k = 0; k < 8; ++k) acc[k] = 0.f;
    for (int s = 0; s < S; ++s) {
        bf16x8 v = ldb8(Opb + ((size_t)s * BT + row) * HK + c8);
        #pragma unroll
        for (int k = 0; k < 8; ++k) acc[k] += bf2f(v[k]);
    }
    const float inv = 1.0f / li;
    f32x4 r0 = f32x4{acc[0] * inv, acc[1] * inv, acc[2] * inv, acc[3] * inv};
    f32x4 r1 = f32x4{acc[4] * inv, acc[5] * inv, acc[6] * inv, acc[7] * inv};
    f32x4* dst = reinterpret_cast<f32x4*>(out + (size_t)row * 320 + 256 + c8);
    dst[0] = r0;
    dst[1] = r1;
}

extern "C" void kernel_launch(void* const* d_in, const int* in_sizes, int n_in,
                              void* d_out, int out_size, void* d_ws, size_t ws_size,
                              hipStream_t stream) {
    (void)in_sizes; (void)n_in; (void)out_size;
    const float* x  = (const float*)d_in[0];
    const float* wk = (const float*)d_in[1];
    const float* wq = (const float*)d_in[2];
    const float* wv = (const float*)d_in[3];
    float* out = (float*)d_out;

    char* ws = (char*)d_ws;
    u16* Qb  = (u16*)(ws);                                    // 2 MB [BT][64]
    u16* Kb  = (u16*)(ws + ((size_t)2 << 20));                // 2 MB [BT][64]
    u16* Vt  = (u16*)(ws + ((size_t)4 << 20));                // 2 MB [B][64][T]
    u16* Wt  = (u16*)(ws + ((size_t)6 << 20));                // 96 KB
    float* lp = (float*)(ws + ((size_t)6 << 20) + (128 << 10)); // S*64 KB
    u16* Opb = (u16*)(ws + ((size_t)7 << 20));                // S*2 MB

    int S = 8;
    while (S > 1 && ((size_t)7 << 20) + (size_t)S * BT * HK * 2 > ws_size) S >>= 1;

    prep_kernel<<<48, 256, 0, stream>>>(wk, wq, wv, Wt);
    proj_kernel<<<BT / 16, 64, 0, stream>>>(x, Wt, out, Qb, Kb, Vt);
    attn_kernel<<<128 * 4 * S, 64, 0, stream>>>(Qb, Kb, Vt, Opb, lp, S);
    merge_kernel<<<512, 256, 0, stream>>>(Opb, lp, out, S);
}

// Round 10
// 75.359 us; speedup vs baseline: 1.0225x; 1.0225x over previous
//
#include <hip/hip_runtime.h>

#define DIMS 256
#define HK 64
#define NB 4
#define NT 4096
#define BT (NB * NT)

typedef unsigned short u16;
typedef unsigned int u32;

using f32x4  = __attribute__((ext_vector_type(4))) float;
using bf16x8 = __attribute__((ext_vector_type(8))) short;

__device__ __forceinline__ u16 f2bf(float f) {
    u32 u = __float_as_uint(f);
    u = (u + 0x7FFFu + ((u >> 16) & 1u)) >> 16;  // RNE; inputs finite
    return (u16)u;
}
__device__ __forceinline__ u32 pack2(float a, float b) {
    return (u32)f2bf(a) | ((u32)f2bf(b) << 16);
}
__device__ __forceinline__ float bf2f(short h) {
    return __uint_as_float(((u32)(u16)h) << 16);
}
__device__ __forceinline__ bf16x8 ldb8(const u16* p) {
    return *reinterpret_cast<const bf16x8*>(p);
}
__device__ __forceinline__ u32 cvtpk(float a, float b) {
    u32 r;
    asm("v_cvt_pk_bf16_f32 %0, %1, %2" : "=v"(r) : "v"(a), "v"(b));
    return r;
}
__device__ __forceinline__ bf16x8 cvt8(const float* p) {
    f32x4 a = *reinterpret_cast<const f32x4*>(p);
    f32x4 b = *reinterpret_cast<const f32x4*>(p + 4);
    union { u32 w[4]; bf16x8 v; } u;
    u.w[0] = pack2(a[0], a[1]); u.w[1] = pack2(a[2], a[3]);
    u.w[2] = pack2(b[0], b[1]); u.w[3] = pack2(b[2], b[3]);
    return u.v;
}

// ---- prep: W transpose/convert only: Wt[m][col][k] = bf16(W[m][k][col]) ----
__global__ __launch_bounds__(256) void prep_kernel(
    const float* __restrict__ wk, const float* __restrict__ wq,
    const float* __restrict__ wv, u16* __restrict__ Wt)
{
    const int i = (int)(blockIdx.x * 256 + threadIdx.x);  // 0..12287
    const int e0 = i * 4;
    const int m = e0 >> 14;
    const int r = e0 & 16383;
    const int col = r >> 8;
    const int k = r & 255;
    const float* w = (m == 0) ? wk : (m == 1) ? wq : wv;
    u32 w0 = pack2(w[(k + 0) * HK + col], w[(k + 1) * HK + col]);
    u32 w1 = pack2(w[(k + 2) * HK + col], w[(k + 3) * HK + col]);
    u32* p = reinterpret_cast<u32*>(Wt + e0);
    p[0] = w0; p[1] = w1;
}

// ---- proj: fused x->out copy + bf16 MFMA GEMMs (K,Q,V) per 16-row tile ----
// (verbatim R8 — passed)
__global__ __launch_bounds__(64) void proj_kernel(
    const float* __restrict__ x, const u16* __restrict__ Wt,
    float* __restrict__ out,
    u16* __restrict__ Qb, u16* __restrict__ Kb, u16* __restrict__ Vt)
{
    const int l = (int)threadIdx.x;
    const int lo = l & 15;
    const int g = l >> 4;
    const int q0 = (int)blockIdx.x * 16;

    const f32x4* x4 = reinterpret_cast<const f32x4*>(x);
    f32x4* out4 = reinterpret_cast<f32x4*>(out);
    #pragma unroll
    for (int c = 0; c < 16; ++c) {
        f32x4 v = x4[(size_t)(q0 + c) * 64 + l];
        out4[(size_t)(q0 + c) * 80 + l] = v;
    }

    bf16x8 a[8];
    #pragma unroll
    for (int kf = 0; kf < 8; ++kf)
        a[kf] = cvt8(x + (size_t)(q0 + lo) * DIMS + kf * 32 + g * 8);

    #pragma unroll
    for (int m = 0; m < 3; ++m) {
        const u16* wb = Wt + m * (HK * DIMS);
        f32x4 acc[4];
        #pragma unroll
        for (int c = 0; c < 4; ++c) acc[c] = f32x4{0.f, 0.f, 0.f, 0.f};

        __builtin_amdgcn_s_setprio(1);
        #pragma unroll
        for (int c = 0; c < 4; ++c) {
            #pragma unroll
            for (int kf = 0; kf < 8; ++kf) {
                bf16x8 bf = ldb8(wb + (size_t)(16 * c + lo) * DIMS + kf * 32 + g * 8);
                acc[c] = __builtin_amdgcn_mfma_f32_16x16x32_bf16(a[kf], bf, acc[c], 0, 0, 0);
            }
        }
        __builtin_amdgcn_s_setprio(0);

        if (m == 2) {
            #pragma unroll
            for (int c = 0; c < 4; ++c)
                #pragma unroll
                for (int ii = 0; ii < 4; ++ii) {
                    const int grow = q0 + 4 * g + ii;
                    Vt[(size_t)((grow >> 12) * HK + 16 * c + lo) * NT + (grow & (NT - 1))] =
                        f2bf(acc[c][ii]);
                }
        } else {
            const float sc = (m == 1) ? 0.125f * 1.44269504f : 1.0f;
            u16* dst = (m == 1) ? Qb : Kb;
            #pragma unroll
            for (int c = 0; c < 4; ++c)
                #pragma unroll
                for (int ii = 0; ii < 4; ++ii)
                    dst[(size_t)(q0 + 4 * g + ii) * HK + 16 * c + lo] = f2bf(acc[c][ii] * sc);
        }
    }
}

// ---- attn helpers: load one 32-key tile's K/V frags; compute one tile ----
__device__ __forceinline__ void ld32(
    const u16* __restrict__ Kb_b, const u16* __restrict__ Vb, int s0,
    bf16x8 (&kk)[2][2], bf16x8 (&vf)[4], int lo, int g)
{
    #pragma unroll
    for (int kh = 0; kh < 2; ++kh)
        #pragma unroll
        for (int kf = 0; kf < 2; ++kf)
            kk[kh][kf] = ldb8(Kb_b + (size_t)(s0 + 16 * kh + lo) * HK + kf * 32 + g * 8);
    #pragma unroll
    for (int c = 0; c < 4; ++c)
        vf[c] = ldb8(Vb + (size_t)(16 * c + lo) * NT + s0 + g * 8);
}

__device__ __forceinline__ void comp32(
    const bf16x8 (&kk)[2][2], const bf16x8 (&vf)[4],
    int s0, int q0, bool domask,
    const bf16x8 (&qf)[2][2], float (&pls)[2], f32x4 (&o)[2][4],
    int lo, int g)
{
    const f32x4 c28 = f32x4{-28.f, -28.f, -28.f, -28.f};  // fold exp2(s-28) bias
    f32x4 sv[2][2];
    __builtin_amdgcn_s_setprio(1);
    #pragma unroll
    for (int rh = 0; rh < 2; ++rh)
        #pragma unroll
        for (int kh = 0; kh < 2; ++kh) {
            sv[rh][kh] = __builtin_amdgcn_mfma_f32_16x16x32_bf16(kk[kh][0], qf[rh][0], c28, 0, 0, 0);
            sv[rh][kh] = __builtin_amdgcn_mfma_f32_16x16x32_bf16(kk[kh][1], qf[rh][1], sv[rh][kh], 0, 0, 0);
        }
    __builtin_amdgcn_s_setprio(0);

    #pragma unroll
    for (int rh = 0; rh < 2; ++rh) {
        float p0[4], p1[4];
        #pragma unroll
        for (int ii = 0; ii < 4; ++ii) {
            float v0 = sv[rh][0][ii];
            float v1 = sv[rh][1][ii];
            if (domask) {  // wave-uniform branch; per-lane predication inside
                const int qr = q0 + 16 * rh + lo;
                if (s0 + 4 * g + ii > qr)      v0 = -1e30f;
                if (s0 + 16 + 4 * g + ii > qr) v1 = -1e30f;
            }
            p0[ii] = __builtin_amdgcn_exp2f(v0);
            p1[ii] = __builtin_amdgcn_exp2f(v1);
            pls[rh] += p0[ii] + p1[ii];
        }
        u32 a0 = cvtpk(p0[0], p0[1]), a1 = cvtpk(p0[2], p0[3]);
        u32 b0 = cvtpk(p1[0], p1[1]), b1 = cvtpk(p1[2], p1[3]);
        asm("v_permlane32_swap_b32 %0, %1" : "+v"(a0), "+v"(b0));
        asm("v_permlane16_swap_b32 %0, %1" : "+v"(a0), "+v"(b0));
        asm("v_permlane32_swap_b32 %0, %1" : "+v"(a1), "+v"(b1));
        asm("v_permlane16_swap_b32 %0, %1" : "+v"(a1), "+v"(b1));
        union { u32 w[4]; bf16x8 v; } u;
        u.w[0] = a0; u.w[1] = a1; u.w[2] = b0; u.w[3] = b1;
        const bf16x8 pa = u.v;
        __builtin_amdgcn_s_setprio(1);
        #pragma unroll
        for (int c = 0; c < 4; ++c)
            o[rh][c] = __builtin_amdgcn_mfma_f32_16x16x32_bf16(pa, vf[c], o[rh][c], 0, 0, 0);
        __builtin_amdgcn_s_setprio(0);
    }
}

// ---- attention: 1 wave, 32 q-rows, register ping-pong prefetch ----
__global__ __launch_bounds__(64) void attn_kernel(
    const u16* __restrict__ Qb, const u16* __restrict__ Kb,
    const u16* __restrict__ Vt, u16* __restrict__ Opb, float* __restrict__ lp,
    const int S)
{
    const int l = (int)threadIdx.x;
    const int lo = l & 15;
    const int g = l >> 4;

    const int bid = (int)blockIdx.x;
    const int per = 4 * S;
    const int j = 127 - bid / per;   // long blocks first
    const int r = bid % per;
    const int b = r / S;
    const int s = r % S;

    const int q0 = j * 32;
    const int nkv = j + 1;                 // 32-key tiles
    const int it0 = (s * nkv) / S;
    const int it1 = ((s + 1) * nkv) / S;

    const u16* Kb_b = Kb + (size_t)b * NT * HK;
    const u16* Vb = Vt + (size_t)b * HK * NT;

    bf16x8 qf[2][2];  // B-operand: col = q-row, k = dim
    #pragma unroll
    for (int rh = 0; rh < 2; ++rh)
        #pragma unroll
        for (int kf = 0; kf < 2; ++kf)
            qf[rh][kf] = ldb8(Qb + (size_t)(b * NT + q0 + 16 * rh + lo) * HK + kf * 32 + g * 8);

    f32x4 o[2][4];
    float pls[2] = {0.f, 0.f};
    #pragma unroll
    for (int rh = 0; rh < 2; ++rh)
        #pragma unroll
        for (int c = 0; c < 4; ++c) o[rh][c] = f32x4{0.f, 0.f, 0.f, 0.f};

    // ping-pong register double-buffer: load tile it+1 before computing it
    bf16x8 kkA[2][2], vfA[4], kkB[2][2], vfB[4];
    int it = it0;
    if (it < it1) {
        ld32(Kb_b, Vb, it * 32, kkA, vfA, lo, g);
        while (true) {
            if (it + 1 < it1) ld32(Kb_b, Vb, (it + 1) * 32, kkB, vfB, lo, g);
            comp32(kkA, vfA, it * 32, q0, it == nkv - 1, qf, pls, o, lo, g);
            ++it;
            if (it >= it1) break;
            if (it + 1 < it1) ld32(Kb_b, Vb, (it + 1) * 32, kkA, vfA, lo, g);
            comp32(kkB, vfB, it * 32, q0, it == nkv - 1, qf, pls, o, lo, g);
            ++it;
            if (it >= it1) break;
        }
    }

    const size_t rowbase = (size_t)s * BT + (size_t)b * NT + q0;
    #pragma unroll
    for (int rh = 0; rh < 2; ++rh) {
        #pragma unroll
        for (int c = 0; c < 4; ++c)
            #pragma unroll
            for (int ii = 0; ii < 4; ++ii)
                Opb[(rowbase + 16 * rh + 4 * g + ii) * HK + 16 * c + lo] = f2bf(o[rh][c][ii]);
        float sum = pls[rh];
        sum += __shfl_xor(sum, 16);
        sum += __shfl_xor(sum, 32);
        if (l < 16) lp[rowbase + 16 * rh + lo] = sum;
    }
}

// ---- merge: out[...,256:320] = sum_s(Opb) / sum_s(lp) ----
__global__ __launch_bounds__(256) void merge_kernel(
    const u16* __restrict__ Opb, const float* __restrict__ lp,
    float* __restrict__ out, const int S)
{
    const int idx = (int)(blockIdx.x * 256 + threadIdx.x);  // [0, BT*8)
    const int row = idx >> 3;
    const int c8 = (idx & 7) * 8;

    float li = 0.f;
    for (int s = 0; s < S; ++s) li += lp[(size_t)s * BT + row];

    float acc[8];
    #pragma unroll
    for (int k = 0; k < 8; ++k) acc[k] = 0.f;
    for (int s = 0; s < S; ++s) {
        bf16x8 v = ldb8(Opb + ((size_t)s * BT + row) * HK + c8);
        #pragma unroll
        for (int k = 0; k < 8; ++k) acc[k] += bf2f(v[k]);
    }
    const float inv = 1.0f / li;
    f32x4 r0 = f32x4{acc[0] * inv, acc[1] * inv, acc[2] * inv, acc[3] * inv};
    f32x4 r1 = f32x4{acc[4] * inv, acc[5] * inv, acc[6] * inv, acc[7] * inv};
    f32x4* dst = reinterpret_cast<f32x4*>(out + (size_t)row * 320 + 256 + c8);
    dst[0] = r0;
    dst[1] = r1;
}

extern "C" void kernel_launch(void* const* d_in, const int* in_sizes, int n_in,
                              void* d_out, int out_size, void* d_ws, size_t ws_size,
                              hipStream_t stream) {
    (void)in_sizes; (void)n_in; (void)out_size;
    const float* x  = (const float*)d_in[0];
    const float* wk = (const float*)d_in[1];
    const float* wq = (const float*)d_in[2];
    const float* wv = (const float*)d_in[3];
    float* out = (float*)d_out;

    char* ws = (char*)d_ws;
    u16* Qb  = (u16*)(ws);                                    // 2 MB [BT][64]
    u16* Kb  = (u16*)(ws + ((size_t)2 << 20));                // 2 MB [BT][64]
    u16* Vt  = (u16*)(ws + ((size_t)4 << 20));                // 2 MB [B][64][T]
    u16* Wt  = (u16*)(ws + ((size_t)6 << 20));                // 96 KB
    float* lp = (float*)(ws + ((size_t)6 << 20) + (128 << 10)); // S*64 KB
    u16* Opb = (u16*)(ws + ((size_t)7 << 20));                // S*2 MB

    int S = 8;
    while (S > 1 && ((size_t)7 << 20) + (size_t)S * BT * HK * 2 > ws_size) S >>= 1;

    prep_kernel<<<48, 256, 0, stream>>>(wk, wq, wv, Wt);
    proj_kernel<<<BT / 16, 64, 0, stream>>>(x, Wt, out, Qb, Kb, Vt);
    attn_kernel<<<128 * 4 * S, 64, 0, stream>>>(Qb, Kb, Vt, Opb, lp, S);
    merge_kernel<<<512, 256, 0, stream>>>(Opb, lp, out, S);
}